// Round 11
// baseline (313.904 us; speedup 1.0000x reference)
//
#include <hip/hip_runtime.h>

// GCN: 100K nodes, 3.2M edges, 128 -> 16 -> 16 -> 16 -> 2, mean-pool to 64 graphs.
// R11 vs R10:
//  (1) k_build: CHUNK 2048, gpos dropped (sbidB instead) -> 33.8KB LDS, 4 blocks/CU.
//  (2) k_bsort: two-pass, 2KB LDS (max occupancy), writes compacted CSR to ents2.
//  (3) sniff merged into k_zero; k_final fused into k_agg2p (completion counter).
//  (4) rowstart+count packed into one word (start | cnt<<22).
// h bf16-packed (L2-resident); MFMA k_t0; dtype-adaptive IO.

#define NN 100000
#define NE 3200000
#define NF 128
#define NH 16
#define NO 2
#define NG 64
#define NBLK 391        // ceil(NN/256)
#define BN 256          // nodes per bucket
#define NBUK 391        // ceil(NN/BN)
#define CHUNK 2048
#define NBLKA 1563      // ceil(NE/CHUNK)
#define CAPF 10240      // bucket region capacity (mean 8184, sigma ~90)
#define NT0 6250        // 16-node tiles

typedef __attribute__((ext_vector_type(8))) short short8;
typedef __attribute__((ext_vector_type(4))) float float4v;

// ---------------- dtype-dispatched IO helpers ----------------

__device__ __forceinline__ float ldf(const void* p, int i, int f32) {
  if (f32) return ((const float*)p)[i];
  unsigned int u = ((const unsigned short*)p)[i];
  return __uint_as_float(u << 16);
}
__device__ __forceinline__ int ldi(const void* p, int i, int i64) {
  if (i64) return (int)((const long long*)p)[i];
  return ((const int*)p)[i];
}
__device__ __forceinline__ void stf(void* p, int i, float v, int f32) {
  if (f32) {
    ((float*)p)[i] = v;
  } else {
    unsigned int w = __float_as_uint(v);
    unsigned int r = (w + 0x7fffu + ((w >> 16) & 1u)) >> 16;
    ((unsigned short*)p)[i] = (unsigned short)r;
  }
}
__device__ __forceinline__ float bf16lo(unsigned int u) { return __uint_as_float(u << 16); }
__device__ __forceinline__ float bf16hi(unsigned int u) { return __uint_as_float(u & 0xffff0000u); }
__device__ __forceinline__ unsigned int packbf(float x, float y) {
  unsigned int a = __float_as_uint(x);
  a = (a + 0x7fffu + ((a >> 16) & 1u)) >> 16;
  unsigned int b = __float_as_uint(y);
  b = (b + 0x7fffu + ((b >> 16) & 1u)) & 0xffff0000u;
  return a | b;
}
__device__ __forceinline__ int okf(float v) { return (v == v) && (fabsf(v) < 1e30f); }
__device__ __forceinline__ void nflag(int* diag, int bad, int bit) {
  if (__any(bad)) {
    if ((threadIdx.x & 63) == 0) atomicOr(diag + 2, 1 << bit);
  }
}
__device__ __forceinline__ int clampi(int v, int hi) {
  return (unsigned)v < (unsigned)hi ? v : 0;
}

// ---------------- zero control block + dtype sniff (one dispatch) ----------------

// ctrl ints: diag[0..15] | pool fl[16..207] | done[208] | cursor[224..614]
__global__ __launch_bounds__(1024) void k_zero(const void* x, const void* ei, int* zbase) {
  int tid = threadIdx.x;
  if (tid < 640) zbase[tid] = 0;
  __syncthreads();
  if (tid < 64) {
    unsigned int xv = ((const unsigned int*)x)[tid];
    unsigned int e = (xv >> 7) & 0xffu;
    int hit = (e >= 116u && e <= 133u);
    int hits = __popcll(__ballot(hit));
    unsigned int ev = ((const unsigned int*)ei)[2 * tid + 1];
    int nzc = __popcll(__ballot(ev != 0u));
    if (tid == 0) {
      zbase[0] = (hits < 32) ? 1 : 0;  // floats are fp32
      zbase[1] = (nzc == 0) ? 1 : 0;   // ints are int64
    }
  }
}

// ---------------- build: bucketed scatter (2048-edge chunks, 33.8KB LDS) ----------------

__global__ __launch_bounds__(512, 5) void k_build(const void* ei, const int* __restrict__ diag,
                                                  int* __restrict__ cursor, int* __restrict__ ents) {
  __shared__ int spktA[CHUNK];             // 8K  (dst&255)<<17|src
  __shared__ unsigned short sbid[CHUNK];   // 4K  bucket id (thread order)
  __shared__ unsigned short srank[CHUNK];  // 4K  rank within bucket
  __shared__ int spktB[CHUNK];             // 8K  bucket-ordered pkt
  __shared__ unsigned short sbidB[CHUNK];  // 4K  bucket id (bucket order)
  __shared__ int lscan[512];               // 2K  counts -> inclusive scan
  __shared__ int sexcl[NBUK];              // 1.6K
  __shared__ int goff[NBUK];               // 1.6K
  int tid = threadIdx.x, blk = blockIdx.x;
  lscan[tid] = 0;
  __syncthreads();
  int i64 = diag[1];
  int base = blk * CHUNK;
  int n = NE - base; n = n > CHUNK ? CHUNK : n;
  for (int i = tid; i < n; i += 512) {
    int sv = clampi(ldi(ei, base + i, i64), NN);
    int dv = clampi(ldi(ei, NE + base + i, i64), NN);
    int b = dv >> 8;
    spktA[i] = ((dv & 255) << 17) | sv;
    sbid[i] = (unsigned short)b;
    srank[i] = (unsigned short)atomicAdd(&lscan[b], 1);
  }
  __syncthreads();
  for (int off = 1; off < 512; off <<= 1) {
    int v = (tid >= off) ? lscan[tid - off] : 0;
    __syncthreads();
    lscan[tid] += v;
    __syncthreads();
  }
  if (tid < NBUK) {
    int incl = lscan[tid];
    int excl = (tid > 0) ? lscan[tid - 1] : 0;
    int cnt = incl - excl;
    sexcl[tid] = excl;
    int rbase = cnt ? atomicAdd(&cursor[tid], cnt) : 0;
    goff[tid] = tid * CAPF + rbase - excl;
  }
  __syncthreads();
  for (int i = tid; i < n; i += 512) {
    int b = sbid[i];
    int rr = sexcl[b] + srank[i];
    spktB[rr] = spktA[i];
    sbidB[rr] = (unsigned short)b;
  }
  __syncthreads();
  for (int r = tid; r < n; r += 512) {
    int b = sbidB[r];
    int gp = goff[b] + r;
    int hi = b * CAPF + CAPF - 1;
    ents[gp <= hi ? gp : hi] = spktB[r];  // overflow clamp (flagged in k_bsort)
  }
}

// per-bucket counting sort, two-pass, 2KB LDS; emits packed rsc + dinv, CSR -> ents2.
__global__ __launch_bounds__(512) void k_bsort(const int* __restrict__ ents, const int* __restrict__ cursor,
                                               int* __restrict__ ents2, unsigned int* __restrict__ rsc,
                                               float* __restrict__ dinv, int* __restrict__ diag) {
  __shared__ int lcnt[BN];   // 1K
  __shared__ int lcur[BN];   // 1K
  int tid = threadIdx.x, b = blockIdx.x;
  int bs = b * CAPF;
  int n = cursor[b];
  if (n > CAPF) { n = CAPF; if (tid == 0) atomicOr(diag + 2, 1 << 9); }
  if (tid < BN) lcnt[tid] = 0;
  __syncthreads();
  for (int i = tid; i < n; i += 512) atomicAdd(&lcnt[ents[bs + i] >> 17], 1);
  __syncthreads();
  int c = (tid < BN) ? lcnt[tid] : 0;
  for (int off = 1; off < BN; off <<= 1) {
    int v = (tid < BN && tid >= off) ? lcnt[tid - off] : 0;
    __syncthreads();
    if (tid < BN) lcnt[tid] += v;
    __syncthreads();
  }
  if (tid < BN) {
    int excl = lcnt[tid] - c;
    lcur[tid] = excl;
    int node = (b << 8) + tid;
    if (node < NN) {
      int cc = c > 1023 ? 1023 : c;
      rsc[node] = (unsigned int)(bs + excl) | ((unsigned int)cc << 22);
      dinv[node] = rsqrtf((float)(c + 1));
      if (c > 1023) atomicOr(diag + 2, 1 << 10);
    }
  }
  __syncthreads();
  for (int i = tid; i < n; i += 512) {
    int e = ents[bs + i];
    int r = atomicAdd(&lcur[e >> 17], 1);
    ents2[bs + r] = e & 0x1FFFF;
  }
}

// ---------------- input transform: hs0 = dinv * (x @ W0), bf16-packed ----------------

__global__ __launch_bounds__(256) void k_t0(const void* __restrict__ x, const void* __restrict__ W0,
                                            const float* __restrict__ dinv,
                                            int* __restrict__ diag, unsigned int* __restrict__ out) {
  __shared__ float ws[NF * NH];
  __shared__ float xs[16 * 129];
  int tid = threadIdx.x;
  int f32 = diag[0];
  if (!f32) {
    const unsigned short* xu = (const unsigned short*)x;
    const unsigned short* wu = (const unsigned short*)W0;
    int wave = tid >> 6, lane = tid & 63;
    int nfe = lane & 15, quad = lane >> 4;
    short8 bfr[4];
#pragma unroll
    for (int mf = 0; mf < 4; ++mf) {
      short8 t;
#pragma unroll
      for (int j = 0; j < 8; ++j) t[j] = (short)wu[(mf * 32 + quad * 8 + j) * NH + nfe];
      bfr[mf] = t;
    }
    int tile = blockIdx.x * 4 + wave;
    if (tile < NT0) {
      int node0 = tile * 16;
      const short8* xrow = (const short8*)(xu + (node0 + nfe) * NF);  // m = nfe
      float4v c = {0.f, 0.f, 0.f, 0.f};
#pragma unroll
      for (int mf = 0; mf < 4; ++mf) {
        short8 a = xrow[mf * 4 + quad];
        c = __builtin_amdgcn_mfma_f32_16x16x32_bf16(a, bfr[mf], c, 0, 0, 0);
      }
      int bad = 0;
#pragma unroll
      for (int r = 0; r < 4; ++r) {
        int node = node0 + quad * 4 + r;
        float v = c[r] * dinv[node];
        float o = __shfl_xor(v, 1);
        if (!(nfe & 1)) out[node * 8 + (nfe >> 1)] = packbf(v, o);
        bad |= !okf(v);
      }
      nflag(diag, bad, 0);
    }
  } else {
    for (int t = 0; t < 4; ++t) {
      int tile = blockIdx.x * 4 + t;
      if (tile >= NT0) break;
      int node0 = tile * 16;
      __syncthreads();
#pragma unroll
      for (int r = 0; r < 8; ++r) ws[tid + 256 * r] = ldf(W0, tid + 256 * r, 1);
#pragma unroll
      for (int r = 0; r < 8; ++r) {
        int idx = tid + 256 * r;
        int row = idx >> 7, col = idx & 127;
        xs[row * 129 + col] = ldf(x, (node0 + row) * NF + col, 1);
      }
      __syncthreads();
      int nl = tid >> 4, f = tid & 15;
      float acc = 0.f;
#pragma unroll 4
      for (int k = 0; k < NF; ++k) acc += xs[nl * 129 + k] * ws[k * NH + f];
      acc *= dinv[node0 + nl];
      float other = __shfl_xor(acc, 1);
      if ((f & 1) == 0) out[(node0 + nl) * 8 + (f >> 1)] = packbf(acc, other);
      nflag(diag, !okf(acc), 0);
    }
  }
}

// ---------------- fused aggregate + PReLU + next transform ----------------

// 4 threads/node, thread p owns features 4p..4p+3 (uint2 = 8B gather/edge, x8 unroll).
__global__ __launch_bounds__(256) void k_aggT(const uint2* __restrict__ hin,
                                              const int* __restrict__ srcs,
                                              const unsigned int* __restrict__ rsc,
                                              const float* __restrict__ dinv,
                                              const void* __restrict__ b, const void* __restrict__ a,
                                              const void* __restrict__ Wn,
                                              int* __restrict__ diag, int bit,
                                              uint2* __restrict__ hout) {
  __shared__ float ws[NH * NH];
  int tid = threadIdx.x;
  int f32 = diag[0];
  ws[tid] = ldf(Wn, tid, f32);
  __syncthreads();
  int gid = blockIdx.x * 256 + tid;  // NN*4 = 400000
  if (gid >= NN * 4) return;
  int node = gid >> 2, p = gid & 3;
  uint2 self = hin[gid];
  float acc0 = bf16lo(self.x), acc1 = bf16hi(self.x);
  float acc2 = bf16lo(self.y), acc3 = bf16hi(self.y);
  unsigned int rv = rsc[node];
  int e = (int)(rv & 0x3FFFFFu);
  int e1 = e + (int)(rv >> 22);
  for (; e + 8 <= e1; e += 8) {
    uint2 v[8];
#pragma unroll
    for (int k = 0; k < 8; ++k) v[k] = hin[srcs[e + k] * 4 + p];
#pragma unroll
    for (int k = 0; k < 8; ++k) {
      acc0 += bf16lo(v[k].x);
      acc1 += bf16hi(v[k].x);
      acc2 += bf16lo(v[k].y);
      acc3 += bf16hi(v[k].y);
    }
  }
  for (; e + 2 <= e1; e += 2) {
    uint2 va = hin[srcs[e] * 4 + p];
    uint2 vb = hin[srcs[e + 1] * 4 + p];
    acc0 += bf16lo(va.x) + bf16lo(vb.x);
    acc1 += bf16hi(va.x) + bf16hi(vb.x);
    acc2 += bf16lo(va.y) + bf16lo(vb.y);
    acc3 += bf16hi(va.y) + bf16hi(vb.y);
  }
  if (e < e1) {
    uint2 v = hin[srcs[e] * 4 + p];
    acc0 += bf16lo(v.x);
    acc1 += bf16hi(v.x);
    acc2 += bf16lo(v.y);
    acc3 += bf16hi(v.y);
  }
  float dv = dinv[node];
  float av = ldf(a, 0, f32);
  float p0 = dv * acc0 + ldf(b, 4 * p + 0, f32);
  float p1 = dv * acc1 + ldf(b, 4 * p + 1, f32);
  float p2 = dv * acc2 + ldf(b, 4 * p + 2, f32);
  float p3 = dv * acc3 + ldf(b, 4 * p + 3, f32);
  p0 = p0 > 0.f ? p0 : av * p0;
  p1 = p1 > 0.f ? p1 : av * p1;
  p2 = p2 > 0.f ? p2 : av * p2;
  p3 = p3 > 0.f ? p3 : av * p3;
  float t0 = 0.f, t1 = 0.f, t2 = 0.f, t3 = 0.f;
#pragma unroll
  for (int j = 0; j < 4; ++j) {
    float q0 = __shfl(p0, j, 4);
    float q1 = __shfl(p1, j, 4);
    float q2 = __shfl(p2, j, 4);
    float q3 = __shfl(p3, j, 4);
    const float* w0 = &ws[(4 * j) * NH + 4 * p];
    const float* w1 = &ws[(4 * j + 1) * NH + 4 * p];
    const float* w2 = &ws[(4 * j + 2) * NH + 4 * p];
    const float* w3 = &ws[(4 * j + 3) * NH + 4 * p];
    t0 += q0 * w0[0] + q1 * w1[0] + q2 * w2[0] + q3 * w3[0];
    t1 += q0 * w0[1] + q1 * w1[1] + q2 * w2[1] + q3 * w3[1];
    t2 += q0 * w0[2] + q1 * w1[2] + q2 * w2[2] + q3 * w3[2];
    t3 += q0 * w0[3] + q1 * w1[3] + q2 * w2[3] + q3 * w3[3];
  }
  t0 *= dv; t1 *= dv; t2 *= dv; t3 *= dv;
  uint2 o;
  o.x = packbf(t0, t1);
  o.y = packbf(t2, t3);
  hout[gid] = o;
  nflag(diag, !okf(t0) || !okf(t3), bit);
}

// Last hidden layer: aggregate + PReLU + W3 (16->2), out float2 prescaled by dinv.
__global__ __launch_bounds__(256) void k_aggT3(const uint2* __restrict__ hin,
                                               const int* __restrict__ srcs,
                                               const unsigned int* __restrict__ rsc,
                                               const float* __restrict__ dinv,
                                               const void* __restrict__ b, const void* __restrict__ a,
                                               const void* __restrict__ W3,
                                               int* __restrict__ diag, float2* __restrict__ hout) {
  __shared__ float ws[NH * NO];
  int tid = threadIdx.x;
  int f32 = diag[0];
  if (tid < NH * NO) ws[tid] = ldf(W3, tid, f32);
  __syncthreads();
  int gid = blockIdx.x * 256 + tid;
  if (gid >= NN * 4) return;
  int node = gid >> 2, p = gid & 3;
  uint2 self = hin[gid];
  float acc0 = bf16lo(self.x), acc1 = bf16hi(self.x);
  float acc2 = bf16lo(self.y), acc3 = bf16hi(self.y);
  unsigned int rv = rsc[node];
  int e = (int)(rv & 0x3FFFFFu);
  int e1 = e + (int)(rv >> 22);
  for (; e + 8 <= e1; e += 8) {
    uint2 v[8];
#pragma unroll
    for (int k = 0; k < 8; ++k) v[k] = hin[srcs[e + k] * 4 + p];
#pragma unroll
    for (int k = 0; k < 8; ++k) {
      acc0 += bf16lo(v[k].x);
      acc1 += bf16hi(v[k].x);
      acc2 += bf16lo(v[k].y);
      acc3 += bf16hi(v[k].y);
    }
  }
  for (; e + 2 <= e1; e += 2) {
    uint2 va = hin[srcs[e] * 4 + p];
    uint2 vb = hin[srcs[e + 1] * 4 + p];
    acc0 += bf16lo(va.x) + bf16lo(vb.x);
    acc1 += bf16hi(va.x) + bf16hi(vb.x);
    acc2 += bf16lo(va.y) + bf16lo(vb.y);
    acc3 += bf16hi(va.y) + bf16hi(vb.y);
  }
  if (e < e1) {
    uint2 v = hin[srcs[e] * 4 + p];
    acc0 += bf16lo(v.x);
    acc1 += bf16hi(v.x);
    acc2 += bf16lo(v.y);
    acc3 += bf16hi(v.y);
  }
  float dv = dinv[node];
  float av = ldf(a, 0, f32);
  float p0 = dv * acc0 + ldf(b, 4 * p + 0, f32);
  float p1 = dv * acc1 + ldf(b, 4 * p + 1, f32);
  float p2 = dv * acc2 + ldf(b, 4 * p + 2, f32);
  float p3 = dv * acc3 + ldf(b, 4 * p + 3, f32);
  p0 = p0 > 0.f ? p0 : av * p0;
  p1 = p1 > 0.f ? p1 : av * p1;
  p2 = p2 > 0.f ? p2 : av * p2;
  p3 = p3 > 0.f ? p3 : av * p3;
  float u0 = p0 * ws[(4 * p) * NO]     + p1 * ws[(4 * p + 1) * NO] +
             p2 * ws[(4 * p + 2) * NO] + p3 * ws[(4 * p + 3) * NO];
  float u1 = p0 * ws[(4 * p) * NO + 1]     + p1 * ws[(4 * p + 1) * NO + 1] +
             p2 * ws[(4 * p + 2) * NO + 1] + p3 * ws[(4 * p + 3) * NO + 1];
  u0 += __shfl_xor(u0, 1, 4);
  u0 += __shfl_xor(u0, 2, 4);
  u1 += __shfl_xor(u1, 1, 4);
  u1 += __shfl_xor(u1, 2, 4);
  if (p == 0) hout[node] = make_float2(dv * u0, dv * u1);
  nflag(diag, !okf(u0) || !okf(u1), 6);
}

// Final 2-wide aggregation + b3 + mean-pool + (last block) final output write.
__global__ __launch_bounds__(256) void k_agg2p(const float2* __restrict__ tin,
                                               const int* __restrict__ srcs,
                                               const unsigned int* __restrict__ rsc,
                                               const float* __restrict__ dinv,
                                               const void* __restrict__ b3,
                                               const void* __restrict__ batch,
                                               int* __restrict__ diag, float* __restrict__ pool,
                                               int* __restrict__ done, void* __restrict__ out) {
  __shared__ float ssum[NG * NO];
  __shared__ float scnt[NG];
  __shared__ int islast;
  int tid = threadIdx.x;
  int f32 = diag[0], i64 = diag[1];
  if (tid < NG * NO) ssum[tid] = 0.f;
  if (tid < NG) scnt[tid] = 0.f;
  __syncthreads();
  int node = blockIdx.x * 256 + tid;
  if (node < NN) {
    float2 t = tin[node];
    float a0 = t.x, a1 = t.y;
    unsigned int rv = rsc[node];
    int e = (int)(rv & 0x3FFFFFu);
    int e1 = e + (int)(rv >> 22);
    for (; e + 4 <= e1; e += 4) {
      int s0 = srcs[e], s1 = srcs[e + 1], s2 = srcs[e + 2], s3 = srcs[e + 3];
      float2 h0 = tin[s0], h1 = tin[s1], h2 = tin[s2], h3 = tin[s3];
      a0 += h0.x + h1.x + h2.x + h3.x;
      a1 += h0.y + h1.y + h2.y + h3.y;
    }
    for (; e < e1; ++e) {
      float2 hv = tin[srcs[e]];
      a0 += hv.x;
      a1 += hv.y;
    }
    float dv = dinv[node];
    a0 = dv * a0 + ldf(b3, 0, f32);
    a1 = dv * a1 + ldf(b3, 1, f32);
    int g = ldi(batch, node, i64);
    g = (unsigned)g < NG ? g : 0;
    atomicAdd(&ssum[g * 2], a0);
    atomicAdd(&ssum[g * 2 + 1], a1);
    atomicAdd(&scnt[g], 1.f);
    nflag(diag, !okf(a0) || !okf(a1), 7);
  }
  __syncthreads();
  if (tid < NG * NO && ssum[tid] != 0.f) atomicAdd(&pool[tid], ssum[tid]);
  if (tid < NG && scnt[tid] != 0.f) atomicAdd(&pool[NG * NO + tid], scnt[tid]);
  // completion: barrier drains vmcnt (pool atomics globally visible), then count.
  __syncthreads();
  if (tid == 0) {
    __threadfence();
    int old = atomicAdd(done, 1);
    islast = (old == NBLK - 1);
  }
  __syncthreads();
  if (!islast) return;
  __threadfence();
  if (tid < NG * NO) {
    float s = atomicAdd(&pool[tid], 0.f);                   // atomic read
    float c = atomicAdd(&pool[NG * NO + (tid >> 1)], 0.f);  // atomic read
    c = c > 1.f ? c : 1.f;
    float v = s / c;
    int stg = atomicOr(diag + 2, 0);
    if (stg != 0 || !okf(v)) {
      int stage = stg ? __ffs(stg) : 15;
      v = 1024.0f + stage * 64.0f + f32 * 16.0f + i64 * 8.0f;
    }
    stf(out, tid, v, f32);
  }
}

__global__ __launch_bounds__(128) void k_diag_ws(void* out, float v) {
  unsigned int w = __float_as_uint(v);
  ((unsigned short*)out)[threadIdx.x] = (unsigned short)(w >> 16);
}

// ---------------- launch ----------------

extern "C" void kernel_launch(void* const* d_in, const int* in_sizes, int n_in,
                              void* d_out, int out_size, void* d_ws, size_t ws_size,
                              hipStream_t stream) {
  const void* x  = d_in[0];
  const void* ei = d_in[1];
  const void* batch = d_in[2];
  const void* W0 = d_in[3];
  const void* b0 = d_in[4];
  const void* a0 = d_in[5];
  const void* W1 = d_in[6];
  const void* b1 = d_in[7];
  const void* a1 = d_in[8];
  const void* W2 = d_in[9];
  const void* b2 = d_in[10];
  const void* a2 = d_in[11];
  const void* W3 = d_in[12];
  const void* b3 = d_in[13];

  // workspace layout (bytes)
  char* w = (char*)d_ws;
  int* diag         = (int*)(w + 0);            // ints 0..15
  float* pool       = (float*)(w + 64);         // 192 floats -> byte 832
  int* done         = (int*)(w + 832);          // 1 int
  int* cursor       = (int*)(w + 896);          // 391 ints -> 2460, pad 2560
  float* dinv       = (float*)(w + 2560);       // 400000 -> 402560
  unsigned int* rsc = (unsigned int*)(w + 402560);  // 400000 -> 802560
  int* ents         = (int*)(w + 802560);       // 16015360 -> 16817920
  int* ents2        = (int*)(w + 16817920);     // 16015360 -> 32833280
  uint2* hsA        = (uint2*)(w + 32833280);   // 3.2MB -> 36033280 (bf16x2 packed)
  uint2* hsB        = (uint2*)(w + 36033280);   // 3.2MB -> 39233280
  float2* hs3       = (float2*)(w + 39233280);  // 800000 -> 40033280
  const size_t NEED = 40033280;

  if (ws_size < NEED) {
    k_diag_ws<<<1, 128, 0, stream>>>(d_out, (float)ws_size);
    return;
  }

  // zero ctrl block + dtype sniff, one dispatch
  k_zero<<<1, 1024, 0, stream>>>(x, ei, (int*)w);

  // build (bucket scatter + two-pass compaction sort)
  k_build<<<NBLKA, 512, 0, stream>>>(ei, diag, cursor, ents);
  k_bsort<<<NBUK, 512, 0, stream>>>(ents, cursor, ents2, rsc, dinv, diag);

  // layers (fused agg + transform; h bf16-packed, L2-resident)
  k_t0<<<(NT0 + 3) / 4, 256, 0, stream>>>(x, W0, dinv, diag, (unsigned int*)hsA);
  k_aggT<<<(NN * 4 + 255) / 256, 256, 0, stream>>>(hsA, ents2, rsc, dinv, b0, a0, W1, diag, 1, hsB);
  k_aggT<<<(NN * 4 + 255) / 256, 256, 0, stream>>>(hsB, ents2, rsc, dinv, b1, a1, W2, diag, 3, hsA);
  k_aggT3<<<(NN * 4 + 255) / 256, 256, 0, stream>>>(hsA, ents2, rsc, dinv, b2, a2, W3, diag, hs3);
  k_agg2p<<<NBLK, 256, 0, stream>>>(hs3, ents2, rsc, dinv, b3, batch, diag, pool, done, d_out);
}